// Round 6
// baseline (551.237 us; speedup 1.0000x reference)
//
#include <hip/hip_runtime.h>
#include <hip/hip_bf16.h>
#include <stdint.h>

#define TT 512
#define NB 128
#define EM 256
#define UN 256

typedef short bf16x8 __attribute__((ext_vector_type(8)));
typedef float floatx4 __attribute__((ext_vector_type(4)));
typedef _Float16 half8 __attribute__((ext_vector_type(8)));

__device__ inline unsigned short f2bf(float f) {
    union { float f; uint32_t u; } v; v.f = f;
    uint32_t r = v.u + 0x7fffu + ((v.u >> 16) & 1u);
    return (unsigned short)(r >> 16);
}
__device__ inline float bf2f(unsigned short b) {
    union { uint32_t u; float f; } v; v.u = ((uint32_t)b) << 16;
    return v.f;
}

// ---------------------------------------------------------------------------
// Kernel 1: repack W -> bf16 B-frags (blocks 0..31) and U -> f16 B-frags
// (blocks 32..63). frag[(kt*16+nt)*64+lane][j] = M[nt*16+(lane&15)][kt*32+(lane>>4)*8+j]
// ---------------------------------------------------------------------------
__global__ void k_pack(const float* __restrict__ W, const float* __restrict__ U,
                       unsigned short* __restrict__ wfrag, _Float16* __restrict__ ufrag) {
    int bid = blockIdx.x;
    int idx = (bid & 31) * 256 + threadIdx.x;  // 0..8191
    int lane = idx & 63;
    int tile = idx >> 6;            // kt*16 + nt
    int nt = tile & 15, kt = tile >> 4;
    int u  = nt * 16 + (lane & 15);
    int e0 = kt * 32 + (lane >> 4) * 8;
    if (bid < 32) {
        unsigned short* dst = wfrag + (size_t)idx * 8;
        #pragma unroll
        for (int j = 0; j < 8; j++) dst[j] = f2bf(W[u * EM + e0 + j]);
    } else {
        _Float16* dst = ufrag + (size_t)idx * 8;
        #pragma unroll
        for (int j = 0; j < 8; j++) dst[j] = (_Float16)U[u * UN + e0 + j];
    }
}

// ---------------------------------------------------------------------------
// Kernel 2: xw[b][t][u] = sum_e emb[sent[b][t]][e] * W[u][e], bf16 out.
// (unchanged from passing version)
// ---------------------------------------------------------------------------
__global__ __launch_bounds__(256, 2) void k_gemm(
    const int* __restrict__ sent, const float* __restrict__ emb,
    const unsigned short* __restrict__ wfrag, unsigned short* __restrict__ xw)
{
    int w    = threadIdx.x >> 6;
    int lane = threadIdx.x & 63;
    int m  = lane & 15;
    int kg = lane >> 4;
    int row = blockIdx.x * 64 + w * 16 + m;
    int tok = sent[row];
    const float* arow = emb + (size_t)tok * EM;

    bf16x8 a[8];
    #pragma unroll
    for (int kt = 0; kt < 8; kt++) {
        const float* p = arow + kt * 32 + kg * 8;
        float4 f0 = *(const float4*)p;
        float4 f1 = *(const float4*)(p + 4);
        bf16x8 t;
        t[0] = (short)f2bf(f0.x); t[1] = (short)f2bf(f0.y);
        t[2] = (short)f2bf(f0.z); t[3] = (short)f2bf(f0.w);
        t[4] = (short)f2bf(f1.x); t[5] = (short)f2bf(f1.y);
        t[6] = (short)f2bf(f1.z); t[7] = (short)f2bf(f1.w);
        a[kt] = t;
    }

    floatx4 acc[16];
    #pragma unroll
    for (int nt = 0; nt < 16; nt++) acc[nt] = floatx4{0.f, 0.f, 0.f, 0.f};

    #pragma unroll
    for (int kt = 0; kt < 8; kt++) {
        #pragma unroll
        for (int nt = 0; nt < 16; nt++) {
            bf16x8 bfr = *(const bf16x8*)(wfrag + ((size_t)(kt * 16 + nt) * 64 + lane) * 8);
            acc[nt] = __builtin_amdgcn_mfma_f32_16x16x32_bf16(a[kt], bfr, acc[nt], 0, 0, 0);
        }
    }

    int rbase = blockIdx.x * 64 + w * 16 + (lane >> 4) * 4;
    int cbase = lane & 15;
    #pragma unroll
    for (int nt = 0; nt < 16; nt++) {
        #pragma unroll
        for (int r = 0; r < 4; r++) {
            xw[(size_t)(rbase + r) * UN + nt * 16 + cbase] = f2bf(acc[nt][r]);
        }
    }
}

// ---------------------------------------------------------------------------
// Kernel 3 (v6): matrix-pipe RNN scan, 2 waves/block (LDS-bus relief).
// 128 blocks x 128 threads. Wave w owns N-tiles 8w..8w+7 (units 128w..128w+127).
// U B-frags loop-invariant in regs/AGPRs (64 frags). Per step per wave:
//   8 broadcast ds_read_b128 A-frags (16 instrs/CU vs 32 in v4/v5),
//   64 MFMA (8 tiles x 2 chains of 4), lane owns units 128w+lane and +64:
//   2 tanh, 2 contiguous ds_write_b16, 1 barrier (2 waves only).
// ---------------------------------------------------------------------------
__global__ __launch_bounds__(128, 1) void k_rnn(
    const _Float16* __restrict__ ufrag, const unsigned short* __restrict__ xw,
    const float* __restrict__ W1, const float* __restrict__ b1,
    const float* __restrict__ W2, const float* __restrict__ b2,
    float* __restrict__ out)
{
    __shared__ __align__(16) _Float16 hb[2][256];
    __shared__ float hid[32];
    const int t    = threadIdx.x;     // 0..127
    const int lane = t & 63;
    const int w    = t >> 6;          // 0..1
    const int kg   = lane >> 4;
    const int b    = blockIdx.x;

    // U B-frags -> registers (loop-invariant): ufr[q][kt], tile nt = 8w+q
    half8 ufr[8][8];
    #pragma unroll
    for (int q = 0; q < 8; q++) {
        #pragma unroll
        for (int kt = 0; kt < 8; kt++) {
            ufr[q][kt] = *(const half8*)(ufrag + ((size_t)(kt * 16 + (8 * w + q)) * 64 + lane) * 8);
        }
    }

    hb[0][t] = (_Float16)0.f; hb[0][t + 128] = (_Float16)0.f;
    hb[1][t] = (_Float16)0.f; hb[1][t + 128] = (_Float16)0.f;
    __syncthreads();

    const unsigned short* xp1 = xw + (size_t)b * TT * UN + 128 * w + lane;  // unit 128w+lane
    const unsigned short* xp2 = xp1 + 64;                                   // unit 128w+64+lane
    unsigned short x0a = xp1[0],  x0b = xp2[0];
    unsigned short x1a = xp1[UN], x1b = xp2[UN];
    int cur = 0;

    const float c3 = -0.33333334f, c5 = 0.13333334f, c7 = -0.05396825f, c9 = 0.02186949f;
    const floatx4 zero4 = {0.f, 0.f, 0.f, 0.f};
    const int sel = lane >> 4;

    for (int s = 0; s < TT; s++) {
        int sn = (s + 2 < TT) ? s + 2 : TT - 1;
        unsigned short x2a = xp1[(size_t)sn * UN];
        unsigned short x2b = xp2[(size_t)sn * UN];

        // A-frags: broadcast reads of h (conflict-free), shared by all 8 tiles
        half8 afr[8];
        const _Float16* hbase = hb[cur] + kg * 8;
        #pragma unroll
        for (int kt = 0; kt < 8; kt++) afr[kt] = *(const half8*)(hbase + kt * 32);

        // 8 N-tiles, 2 independent 4-deep MFMA chains each
        float z[8];
        #pragma unroll
        for (int q = 0; q < 8; q++) {
            floatx4 c0 = zero4, c1 = zero4;
            c0 = __builtin_amdgcn_mfma_f32_16x16x32_f16(afr[0], ufr[q][0], c0, 0, 0, 0);
            c1 = __builtin_amdgcn_mfma_f32_16x16x32_f16(afr[1], ufr[q][1], c1, 0, 0, 0);
            c0 = __builtin_amdgcn_mfma_f32_16x16x32_f16(afr[2], ufr[q][2], c0, 0, 0, 0);
            c1 = __builtin_amdgcn_mfma_f32_16x16x32_f16(afr[3], ufr[q][3], c1, 0, 0, 0);
            c0 = __builtin_amdgcn_mfma_f32_16x16x32_f16(afr[4], ufr[q][4], c0, 0, 0, 0);
            c1 = __builtin_amdgcn_mfma_f32_16x16x32_f16(afr[5], ufr[q][5], c1, 0, 0, 0);
            c0 = __builtin_amdgcn_mfma_f32_16x16x32_f16(afr[6], ufr[q][6], c0, 0, 0, 0);
            c1 = __builtin_amdgcn_mfma_f32_16x16x32_f16(afr[7], ufr[q][7], c1, 0, 0, 0);
            z[q] = c0[0] + c1[0];
        }

        // lane owns units 128w+lane (tile sel) and 128w+64+lane (tile 4+sel)
        float zz1 = (sel == 0) ? z[0] : (sel == 1) ? z[1] : (sel == 2) ? z[2] : z[3];
        float zz2 = (sel == 0) ? z[4] : (sel == 1) ? z[5] : (sel == 2) ? z[6] : z[7];
        zz1 += bf2f(x0a);
        zz2 += bf2f(x0b);

        float hn1, hn2;
        float mxz = fmaxf(fabsf(zz1), fabsf(zz2));
        if (__builtin_expect(mxz > 0.75f, 0)) {
            float e1 = __expf(2.f * zz1);
            hn1 = 1.f - 2.f * __builtin_amdgcn_rcpf(e1 + 1.f);
            float e2 = __expf(2.f * zz2);
            hn2 = 1.f - 2.f * __builtin_amdgcn_rcpf(e2 + 1.f);
        } else {
            float x2f = zz1 * zz1;
            float p = fmaf(x2f, c9, c7);
            p = fmaf(x2f, p, c5);
            p = fmaf(x2f, p, c3);
            hn1 = fmaf(zz1 * x2f, p, zz1);
            float y2f = zz2 * zz2;
            float p2 = fmaf(y2f, c9, c7);
            p2 = fmaf(y2f, p2, c5);
            p2 = fmaf(y2f, p2, c3);
            hn2 = fmaf(zz2 * y2f, p2, zz2);
        }

        hb[cur ^ 1][128 * w + lane]      = (_Float16)hn1;
        hb[cur ^ 1][128 * w + 64 + lane] = (_Float16)hn2;
        __syncthreads();
        cur ^= 1;
        x0a = x1a; x0b = x1b;
        x1a = x2a; x1b = x2b;
    }

    // ---- head: hidden = relu(h @ W1 + b1); logits; softmax
    if (t < 32) {
        float a = b1[t];
        for (int k = 0; k < 256; k++) a += (float)hb[cur][k] * W1[k * 32 + t];
        hid[t] = fmaxf(a, 0.f);
    }
    __syncthreads();
    if (t == 0) {
        float l0 = b2[0], l1 = b2[1];
        #pragma unroll
        for (int i = 0; i < 32; i++) {
            float hv = hid[i];
            l0 += hv * W2[2 * i];
            l1 += hv * W2[2 * i + 1];
        }
        float mx2 = fmaxf(l0, l1);
        float e0 = __expf(l0 - mx2), e1 = __expf(l1 - mx2);
        float inv = 1.f / (e0 + e1);
        out[2 * b]     = e0 * inv;
        out[2 * b + 1] = e1 * inv;
    }
}

extern "C" void kernel_launch(void* const* d_in, const int* in_sizes, int n_in,
                              void* d_out, int out_size, void* d_ws, size_t ws_size,
                              hipStream_t stream) {
    const int*   sent = (const int*)d_in[0];
    const float* emb  = (const float*)d_in[1];
    const float* W    = (const float*)d_in[2];
    const float* U    = (const float*)d_in[3];
    const float* W1   = (const float*)d_in[4];
    const float* b1   = (const float*)d_in[5];
    const float* W2   = (const float*)d_in[6];
    const float* b2   = (const float*)d_in[7];
    float* out = (float*)d_out;

    unsigned short* xw    = (unsigned short*)d_ws;                                        // 32 MB bf16 [B][T][U]
    unsigned short* wfrag = (unsigned short*)((char*)d_ws + (size_t)NB * TT * UN * 2);    // 128 KB
    _Float16*       ufrag = (_Float16*)((char*)d_ws + (size_t)NB * TT * UN * 2 + (size_t)UN * EM * 2); // 128 KB

    k_pack<<<64, 256, 0, stream>>>(W, U, wfrag, ufrag);
    k_gemm<<<(NB * TT) / 64, 256, 0, stream>>>(sent, emb, wfrag, xw);
    k_rnn<<<NB, 128, 0, stream>>>(ufrag, xw, W1, b1, W2, b2, out);
}

// Round 7
// 454.807 us; speedup vs baseline: 1.2120x; 1.2120x over previous
//
#include <hip/hip_runtime.h>
#include <hip/hip_bf16.h>
#include <stdint.h>

#define TT 512
#define NB 128
#define EM 256
#define UN 256

typedef short bf16x8 __attribute__((ext_vector_type(8)));
typedef float floatx4 __attribute__((ext_vector_type(4)));
typedef _Float16 half8 __attribute__((ext_vector_type(8)));

__device__ inline unsigned short f2bf(float f) {
    union { float f; uint32_t u; } v; v.f = f;
    uint32_t r = v.u + 0x7fffu + ((v.u >> 16) & 1u);
    return (unsigned short)(r >> 16);
}
__device__ inline float bf2f(unsigned short b) {
    union { uint32_t u; float f; } v; v.u = ((uint32_t)b) << 16;
    return v.f;
}

// ---------------------------------------------------------------------------
// Kernel 1: repack W -> bf16 B-frags (blocks 0..31) and U -> f16 B-frags
// (blocks 32..63). frag[(kt*16+nt)*64+lane][j] = M[nt*16+(lane&15)][kt*32+(lane>>4)*8+j]
// ---------------------------------------------------------------------------
__global__ void k_pack(const float* __restrict__ W, const float* __restrict__ U,
                       unsigned short* __restrict__ wfrag, _Float16* __restrict__ ufrag) {
    int bid = blockIdx.x;
    int idx = (bid & 31) * 256 + threadIdx.x;  // 0..8191
    int lane = idx & 63;
    int tile = idx >> 6;            // kt*16 + nt
    int nt = tile & 15, kt = tile >> 4;
    int u  = nt * 16 + (lane & 15);
    int e0 = kt * 32 + (lane >> 4) * 8;
    if (bid < 32) {
        unsigned short* dst = wfrag + (size_t)idx * 8;
        #pragma unroll
        for (int j = 0; j < 8; j++) dst[j] = f2bf(W[u * EM + e0 + j]);
    } else {
        _Float16* dst = ufrag + (size_t)idx * 8;
        #pragma unroll
        for (int j = 0; j < 8; j++) dst[j] = (_Float16)U[u * UN + e0 + j];
    }
}

// ---------------------------------------------------------------------------
// Kernel 2 (fused): per-batch-row xw GEMM prologue + R4-exact MFMA scan.
// 128 blocks x 256 threads (4 waves).
// Prologue: wave w computes row-tiles (timestep tiles) w*8..w*8+7 as 4 pairs;
//   each B-frag (global, L2/L3-hot) is read once per pair and used for 2 rows.
//   xw written bf16 to ws (same layout as before), then threadfence+barrier.
// Scan (identical to R4 244us version): wave w owns N-tiles 4w..4w+3;
//   U B-frags loop-invariant in regs; 8 broadcast ds_read_b128 A-frags;
//   32 MFMA as 4 tiles x 2 chains of 4; lane L owns unit 64w+L; poly tanh;
//   1 ds_write_b16 + 1 barrier per step; xw prefetched 2 steps ahead.
// ---------------------------------------------------------------------------
__global__ __launch_bounds__(256, 1) void k_rnn(
    const int* __restrict__ sent, const float* __restrict__ emb,
    const unsigned short* __restrict__ wfrag, const _Float16* __restrict__ ufrag,
    unsigned short* __restrict__ xw,
    const float* __restrict__ W1, const float* __restrict__ b1,
    const float* __restrict__ W2, const float* __restrict__ b2,
    float* __restrict__ out)
{
    __shared__ __align__(16) _Float16 hb[2][256];
    __shared__ float hid[32];
    const int t    = threadIdx.x;
    const int lane = t & 63;
    const int w    = t >> 6;
    const int kg   = lane >> 4;
    const int b    = blockIdx.x;

    // ================= Prologue: xw[b][t][u] for this batch row =================
    {
        const int m = lane & 15;
        unsigned short* xb = xw + (size_t)b * TT * UN;
        for (int rp = 0; rp < 4; rp++) {
            int rt0 = w * 8 + rp * 2;           // two timestep-tiles per pass
            int t0  = rt0 * 16 + m;
            int t1  = t0 + 16;
            int tok0 = sent[b * TT + t0];
            int tok1 = sent[b * TT + t1];
            const float* ar0 = emb + (size_t)tok0 * EM;
            const float* ar1 = emb + (size_t)tok1 * EM;

            bf16x8 a0[8], a1[8];
            #pragma unroll
            for (int kt = 0; kt < 8; kt++) {
                const float* p0 = ar0 + kt * 32 + kg * 8;
                const float* p1 = ar1 + kt * 32 + kg * 8;
                float4 f0 = *(const float4*)p0;
                float4 f1 = *(const float4*)(p0 + 4);
                float4 g0 = *(const float4*)p1;
                float4 g1 = *(const float4*)(p1 + 4);
                bf16x8 ta, tb;
                ta[0] = (short)f2bf(f0.x); ta[1] = (short)f2bf(f0.y);
                ta[2] = (short)f2bf(f0.z); ta[3] = (short)f2bf(f0.w);
                ta[4] = (short)f2bf(f1.x); ta[5] = (short)f2bf(f1.y);
                ta[6] = (short)f2bf(f1.z); ta[7] = (short)f2bf(f1.w);
                tb[0] = (short)f2bf(g0.x); tb[1] = (short)f2bf(g0.y);
                tb[2] = (short)f2bf(g0.z); tb[3] = (short)f2bf(g0.w);
                tb[4] = (short)f2bf(g1.x); tb[5] = (short)f2bf(g1.y);
                tb[6] = (short)f2bf(g1.z); tb[7] = (short)f2bf(g1.w);
                a0[kt] = ta; a1[kt] = tb;
            }

            floatx4 acc0[16], acc1[16];
            #pragma unroll
            for (int nt = 0; nt < 16; nt++) {
                acc0[nt] = floatx4{0.f, 0.f, 0.f, 0.f};
                acc1[nt] = floatx4{0.f, 0.f, 0.f, 0.f};
            }

            #pragma unroll
            for (int kt = 0; kt < 8; kt++) {
                #pragma unroll
                for (int nt = 0; nt < 16; nt++) {
                    bf16x8 fr = *(const bf16x8*)(wfrag + ((size_t)(kt * 16 + nt) * 64 + lane) * 8);
                    acc0[nt] = __builtin_amdgcn_mfma_f32_16x16x32_bf16(a0[kt], fr, acc0[nt], 0, 0, 0);
                    acc1[nt] = __builtin_amdgcn_mfma_f32_16x16x32_bf16(a1[kt], fr, acc1[nt], 0, 0, 0);
                }
            }

            int rb0 = rt0 * 16 + kg * 4;        // D row base within this row-tile
            #pragma unroll
            for (int nt = 0; nt < 16; nt++) {
                #pragma unroll
                for (int r = 0; r < 4; r++) {
                    xb[(size_t)(rb0 + r) * UN + nt * 16 + m]      = f2bf(acc0[nt][r]);
                    xb[(size_t)(rb0 + 16 + r) * UN + nt * 16 + m] = f2bf(acc1[nt][r]);
                }
            }
        }
    }
    __threadfence();

    // ================= Scan (R4-exact) =================
    // U B-frags -> registers (loop-invariant): ufr[q][kt], tile nt = 4w+q
    half8 ufr[4][8];
    #pragma unroll
    for (int q = 0; q < 4; q++) {
        #pragma unroll
        for (int kt = 0; kt < 8; kt++) {
            ufr[q][kt] = *(const half8*)(ufrag + ((size_t)(kt * 16 + (4 * w + q)) * 64 + lane) * 8);
        }
    }

    hb[0][t] = (_Float16)0.f;
    hb[1][t] = (_Float16)0.f;
    __syncthreads();

    const unsigned short* xp = xw + (size_t)b * TT * UN + t;  // coalesced per wave
    unsigned short x0 = xp[0];
    unsigned short x1 = xp[UN];
    int cur = 0;

    const float c3 = -0.33333334f, c5 = 0.13333334f, c7 = -0.05396825f, c9 = 0.02186949f;
    const floatx4 zero4 = {0.f, 0.f, 0.f, 0.f};
    const int sel = lane >> 4;

    for (int s = 0; s < TT; s++) {
        int sn = (s + 2 < TT) ? s + 2 : TT - 1;
        unsigned short x2 = xp[(size_t)sn * UN];

        // A-frags: lane reads h[kg*8 + kt*32 ..] (16-way broadcast, conflict-free)
        half8 afr[8];
        const _Float16* hbase = hb[cur] + kg * 8;
        #pragma unroll
        for (int kt = 0; kt < 8; kt++) {
            afr[kt] = *(const half8*)(hbase + kt * 32);
        }

        // z for this wave's 4 N-tiles; 2 independent 4-deep chains per tile
        float z[4];
        #pragma unroll
        for (int q = 0; q < 4; q++) {
            floatx4 ae = zero4, ao = zero4;
            #pragma unroll
            for (int kt = 0; kt < 4; kt++) {
                ae = __builtin_amdgcn_mfma_f32_16x16x32_f16(afr[2 * kt],     ufr[q][2 * kt],     ae, 0, 0, 0);
                ao = __builtin_amdgcn_mfma_f32_16x16x32_f16(afr[2 * kt + 1], ufr[q][2 * kt + 1], ao, 0, 0, 0);
            }
            z[q] = ae[0] + ao[0];
        }

        float zz = (sel == 0) ? z[0] : (sel == 1) ? z[1] : (sel == 2) ? z[2] : z[3];
        zz += bf2f(x0);

        float hn;
        if (__builtin_expect(fabsf(zz) > 0.75f, 0)) {
            float e = __expf(2.f * zz);
            hn = 1.f - 2.f * __builtin_amdgcn_rcpf(e + 1.f);
        } else {
            float x2f = zz * zz;
            float p = fmaf(x2f, c9, c7);
            p = fmaf(x2f, p, c5);
            p = fmaf(x2f, p, c3);
            hn = fmaf(zz * x2f, p, zz);
        }

        hb[cur ^ 1][t] = (_Float16)hn;
        __syncthreads();
        cur ^= 1;
        x0 = x1;
        x1 = x2;
    }

    // ---- head: hidden = relu(h @ W1 + b1); logits; softmax
    if (t < 32) {
        float a = b1[t];
        for (int k = 0; k < 256; k++) a += (float)hb[cur][k] * W1[k * 32 + t];
        hid[t] = fmaxf(a, 0.f);
    }
    __syncthreads();
    if (t == 0) {
        float l0 = b2[0], l1 = b2[1];
        #pragma unroll
        for (int i = 0; i < 32; i++) {
            float hv = hid[i];
            l0 += hv * W2[2 * i];
            l1 += hv * W2[2 * i + 1];
        }
        float mx2 = fmaxf(l0, l1);
        float e0 = __expf(l0 - mx2), e1 = __expf(l1 - mx2);
        float inv = 1.f / (e0 + e1);
        out[2 * b]     = e0 * inv;
        out[2 * b + 1] = e1 * inv;
    }
}

extern "C" void kernel_launch(void* const* d_in, const int* in_sizes, int n_in,
                              void* d_out, int out_size, void* d_ws, size_t ws_size,
                              hipStream_t stream) {
    const int*   sent = (const int*)d_in[0];
    const float* emb  = (const float*)d_in[1];
    const float* W    = (const float*)d_in[2];
    const float* U    = (const float*)d_in[3];
    const float* W1   = (const float*)d_in[4];
    const float* b1   = (const float*)d_in[5];
    const float* W2   = (const float*)d_in[6];
    const float* b2   = (const float*)d_in[7];
    float* out = (float*)d_out;

    unsigned short* xw    = (unsigned short*)d_ws;                                        // 32 MB bf16 [B][T][U]
    unsigned short* wfrag = (unsigned short*)((char*)d_ws + (size_t)NB * TT * UN * 2);    // 128 KB
    _Float16*       ufrag = (_Float16*)((char*)d_ws + (size_t)NB * TT * UN * 2 + (size_t)UN * EM * 2); // 128 KB

    k_pack<<<64, 256, 0, stream>>>(W, U, wfrag, ufrag);
    k_rnn<<<NB, 256, 0, stream>>>(sent, emb, wfrag, ufrag, xw, W1, b1, W2, b2, out);
}

// Round 8
// 359.675 us; speedup vs baseline: 1.5326x; 1.2645x over previous
//
#include <hip/hip_runtime.h>
#include <hip/hip_bf16.h>
#include <stdint.h>

#define TT 512
#define NB 128
#define EM 256
#define UN 256

typedef short bf16x8 __attribute__((ext_vector_type(8)));
typedef float floatx4 __attribute__((ext_vector_type(4)));
typedef _Float16 half8 __attribute__((ext_vector_type(8)));

// barrier without vmcnt drain: LDS-ordered only (no VMEM in scan steady state)
#define BAR() asm volatile("s_waitcnt lgkmcnt(0)\n\ts_barrier" ::: "memory")

__device__ inline unsigned short f2bf(float f) {
    union { float f; uint32_t u; } v; v.f = f;
    uint32_t r = v.u + 0x7fffu + ((v.u >> 16) & 1u);
    return (unsigned short)(r >> 16);
}
__device__ inline float bf2f(unsigned short b) {
    union { uint32_t u; float f; } v; v.u = ((uint32_t)b) << 16;
    return v.f;
}

// ---------------------------------------------------------------------------
// Kernel 1: repack W -> bf16 B-frags (blocks 0..31) and U -> f16 B-frags
// (blocks 32..63). frag[(kt*16+nt)*64+lane][j] = M[nt*16+(lane&15)][kt*32+(lane>>4)*8+j]
// ---------------------------------------------------------------------------
__global__ void k_pack(const float* __restrict__ W, const float* __restrict__ U,
                       unsigned short* __restrict__ wfrag, _Float16* __restrict__ ufrag) {
    int bid = blockIdx.x;
    int idx = (bid & 31) * 256 + threadIdx.x;  // 0..8191
    int lane = idx & 63;
    int tile = idx >> 6;            // kt*16 + nt
    int nt = tile & 15, kt = tile >> 4;
    int u  = nt * 16 + (lane & 15);
    int e0 = kt * 32 + (lane >> 4) * 8;
    if (bid < 32) {
        unsigned short* dst = wfrag + (size_t)idx * 8;
        #pragma unroll
        for (int j = 0; j < 8; j++) dst[j] = f2bf(W[u * EM + e0 + j]);
    } else {
        _Float16* dst = ufrag + (size_t)idx * 8;
        #pragma unroll
        for (int j = 0; j < 8; j++) dst[j] = (_Float16)U[u * UN + e0 + j];
    }
}

// ---------------------------------------------------------------------------
// Kernel 2: xw[b][t][u] = sum_e emb[sent[b][t]][e] * W[u][e], bf16 out.
// v2: epilogue transposes through LDS so xw stores are coalesced dwordx2
// (R7 showed the old scattered 2-byte stores cost ~2x WRITE_SIZE).
// ---------------------------------------------------------------------------
__global__ __launch_bounds__(256, 2) void k_gemm(
    const int* __restrict__ sent, const float* __restrict__ emb,
    const unsigned short* __restrict__ wfrag, unsigned short* __restrict__ xw)
{
    __shared__ unsigned short gt[64][264];   // 64 rows x 256 cols, +8 pad
    int w    = threadIdx.x >> 6;
    int lane = threadIdx.x & 63;
    int m  = lane & 15;
    int kg = lane >> 4;
    int row = blockIdx.x * 64 + w * 16 + m;
    int tok = sent[row];
    const float* arow = emb + (size_t)tok * EM;

    bf16x8 a[8];
    #pragma unroll
    for (int kt = 0; kt < 8; kt++) {
        const float* p = arow + kt * 32 + kg * 8;
        float4 f0 = *(const float4*)p;
        float4 f1 = *(const float4*)(p + 4);
        bf16x8 t;
        t[0] = (short)f2bf(f0.x); t[1] = (short)f2bf(f0.y);
        t[2] = (short)f2bf(f0.z); t[3] = (short)f2bf(f0.w);
        t[4] = (short)f2bf(f1.x); t[5] = (short)f2bf(f1.y);
        t[6] = (short)f2bf(f1.z); t[7] = (short)f2bf(f1.w);
        a[kt] = t;
    }

    floatx4 acc[16];
    #pragma unroll
    for (int nt = 0; nt < 16; nt++) acc[nt] = floatx4{0.f, 0.f, 0.f, 0.f};

    #pragma unroll
    for (int kt = 0; kt < 8; kt++) {
        #pragma unroll
        for (int nt = 0; nt < 16; nt++) {
            bf16x8 bfr = *(const bf16x8*)(wfrag + ((size_t)(kt * 16 + nt) * 64 + lane) * 8);
            acc[nt] = __builtin_amdgcn_mfma_f32_16x16x32_bf16(a[kt], bfr, acc[nt], 0, 0, 0);
        }
    }

    // D layout: local row = w*16 + kg*4 + r, col = nt*16 + m  -> LDS tile
    int rloc = w * 16 + kg * 4;
    #pragma unroll
    for (int nt = 0; nt < 16; nt++) {
        #pragma unroll
        for (int r = 0; r < 4; r++) {
            gt[rloc + r][nt * 16 + m] = f2bf(acc[nt][r]);
        }
    }
    __syncthreads();

    // coalesced store: each wave stores its 16 rows, 512 B/row contiguous
    int rowbase = blockIdx.x * 64;
    #pragma unroll
    for (int r2 = 0; r2 < 16; r2++) {
        int rr = w * 16 + r2;
        uint2 v = *(const uint2*)&gt[rr][lane * 4];
        *(uint2*)(xw + (size_t)(rowbase + rr) * UN + lane * 4) = v;
    }
}

// ---------------------------------------------------------------------------
// Kernel 3 (v7): R4 matrix-pipe scan + LDS-staged xw (no VMEM in steady loop).
// 128 blocks x 256 threads; wave w owns N-tiles 4w..4w+3 (units 64w..64w+63).
// xw staged in LDS 64 steps (32 KB) at a time: 8 coalesced dwordx4 loads
// issued at ls==60 (regs), ds_write_b128 at ls==63 behind an LDS barrier.
// Scan barriers are `s_waitcnt lgkmcnt(0); s_barrier` -> no vmcnt drain ever.
// Per step: 1 ds_read_u16 (xv) + 8 broadcast ds_read_b128 A-frags + 32 MFMA
// (4 tiles x 2 chains of 4) + select + poly tanh + 1 ds_write_b16 + 1 barrier.
// ---------------------------------------------------------------------------
__global__ __launch_bounds__(256, 1) void k_rnn(
    const _Float16* __restrict__ ufrag, const unsigned short* __restrict__ xw,
    const float* __restrict__ W1, const float* __restrict__ b1,
    const float* __restrict__ W2, const float* __restrict__ b2,
    float* __restrict__ out)
{
    __shared__ __align__(16) _Float16 hb[2][256];
    __shared__ __align__(16) unsigned short xstage[64 * 256];   // 32 KB, one 64-step chunk
    __shared__ float hid[32];
    const int t    = threadIdx.x;
    const int lane = t & 63;
    const int w    = t >> 6;
    const int kg   = lane >> 4;
    const int b    = blockIdx.x;

    // U B-frags -> registers (loop-invariant): ufr[q][kt], tile nt = 4w+q
    half8 ufr[4][8];
    #pragma unroll
    for (int q = 0; q < 4; q++) {
        #pragma unroll
        for (int kt = 0; kt < 8; kt++) {
            ufr[q][kt] = *(const half8*)(ufrag + ((size_t)(kt * 16 + (4 * w + q)) * 64 + lane) * 8);
        }
    }

    const unsigned short* xwb = xw + (size_t)b * TT * UN;
    const int roff = w * 512 + lane * 8;   // ushort offset of this thread's 16B refresh slice

    // stage chunk 0 (steps 0..63)
    uint4 xr[8];
    #pragma unroll
    for (int p = 0; p < 8; p++) xr[p] = *(const uint4*)(xwb + roff + p * 2048);
    #pragma unroll
    for (int p = 0; p < 8; p++) *(uint4*)&xstage[roff + p * 2048] = xr[p];

    hb[0][t] = (_Float16)0.f;
    hb[1][t] = (_Float16)0.f;
    __syncthreads();

    int cur = 0;
    const float c3 = -0.33333334f, c5 = 0.13333334f, c7 = -0.05396825f, c9 = 0.02186949f;
    const floatx4 zero4 = {0.f, 0.f, 0.f, 0.f};
    const int sel = lane >> 4;

    for (int s = 0; s < TT; s++) {
        const int ls = s & 63;
        unsigned short xv = xstage[ls * 256 + t];   // LDS, 2-way bank = free

        // A-frags: lane reads h[kg*8 + kt*32 ..] (16-way broadcast, conflict-free)
        half8 afr[8];
        const _Float16* hbase = hb[cur] + kg * 8;
        #pragma unroll
        for (int kt = 0; kt < 8; kt++) {
            afr[kt] = *(const half8*)(hbase + kt * 32);
        }

        // z for this wave's 4 N-tiles; 2 independent 4-deep chains per tile
        float z[4];
        #pragma unroll
        for (int q = 0; q < 4; q++) {
            floatx4 ae = zero4, ao = zero4;
            #pragma unroll
            for (int kt = 0; kt < 4; kt++) {
                ae = __builtin_amdgcn_mfma_f32_16x16x32_f16(afr[2 * kt],     ufr[q][2 * kt],     ae, 0, 0, 0);
                ao = __builtin_amdgcn_mfma_f32_16x16x32_f16(afr[2 * kt + 1], ufr[q][2 * kt + 1], ao, 0, 0, 0);
            }
            z[q] = ae[0] + ao[0];
        }

        float zz = (sel == 0) ? z[0] : (sel == 1) ? z[1] : (sel == 2) ? z[2] : z[3];
        zz += bf2f(xv);

        float hn;
        if (__builtin_expect(fabsf(zz) > 0.75f, 0)) {
            float e = __expf(2.f * zz);
            hn = 1.f - 2.f * __builtin_amdgcn_rcpf(e + 1.f);
        } else {
            float x2f = zz * zz;
            float p = fmaf(x2f, c9, c7);
            p = fmaf(x2f, p, c5);
            p = fmaf(x2f, p, c3);
            hn = fmaf(zz * x2f, p, zz);
        }

        hb[cur ^ 1][t] = (_Float16)hn;

        // refresh pipeline: loads 3 steps before the write -> vmcnt satisfied
        // by data-dep long before use; barriers never drain it.
        if (ls == 60 && s + 68 <= TT) {
            const unsigned short* cb = xwb + (size_t)(s + 4) * UN;  // next chunk base
            #pragma unroll
            for (int p = 0; p < 8; p++) xr[p] = *(const uint4*)(cb + roff + p * 2048);
        }
        if (ls == 63 && s + 65 <= TT) {
            BAR();   // all waves done reading this chunk's xstage rows
            #pragma unroll
            for (int p = 0; p < 8; p++) *(uint4*)&xstage[roff + p * 2048] = xr[p];
        }
        BAR();
        cur ^= 1;
    }

    // ---- head: hidden = relu(h @ W1 + b1); logits; softmax
    if (t < 32) {
        float a = b1[t];
        for (int k = 0; k < 256; k++) a += (float)hb[cur][k] * W1[k * 32 + t];
        hid[t] = fmaxf(a, 0.f);
    }
    __syncthreads();
    if (t == 0) {
        float l0 = b2[0], l1 = b2[1];
        #pragma unroll
        for (int i = 0; i < 32; i++) {
            float hv = hid[i];
            l0 += hv * W2[2 * i];
            l1 += hv * W2[2 * i + 1];
        }
        float mx2 = fmaxf(l0, l1);
        float e0 = __expf(l0 - mx2), e1 = __expf(l1 - mx2);
        float inv = 1.f / (e0 + e1);
        out[2 * b]     = e0 * inv;
        out[2 * b + 1] = e1 * inv;
    }
}

extern "C" void kernel_launch(void* const* d_in, const int* in_sizes, int n_in,
                              void* d_out, int out_size, void* d_ws, size_t ws_size,
                              hipStream_t stream) {
    const int*   sent = (const int*)d_in[0];
    const float* emb  = (const float*)d_in[1];
    const float* W    = (const float*)d_in[2];
    const float* U    = (const float*)d_in[3];
    const float* W1   = (const float*)d_in[4];
    const float* b1   = (const float*)d_in[5];
    const float* W2   = (const float*)d_in[6];
    const float* b2   = (const float*)d_in[7];
    float* out = (float*)d_out;

    unsigned short* xw    = (unsigned short*)d_ws;                                        // 32 MB bf16 [B][T][U]
    unsigned short* wfrag = (unsigned short*)((char*)d_ws + (size_t)NB * TT * UN * 2);    // 128 KB
    _Float16*       ufrag = (_Float16*)((char*)d_ws + (size_t)NB * TT * UN * 2 + (size_t)UN * EM * 2); // 128 KB

    k_pack<<<64, 256, 0, stream>>>(W, U, wfrag, ufrag);
    k_gemm<<<(NB * TT) / 64, 256, 0, stream>>>(sent, emb, wfrag, xw);
    k_rnn<<<NB, 256, 0, stream>>>(ufrag, xw, W1, b1, W2, b2, out);
}

// Round 9
// 333.434 us; speedup vs baseline: 1.6532x; 1.0787x over previous
//
#include <hip/hip_runtime.h>
#include <hip/hip_bf16.h>
#include <stdint.h>

#define TT 512
#define NB 128
#define EM 256
#define UN 256

typedef short bf16x8 __attribute__((ext_vector_type(8)));
typedef float floatx4 __attribute__((ext_vector_type(4)));
typedef _Float16 half8 __attribute__((ext_vector_type(8)));
typedef int v8i __attribute__((ext_vector_type(8)));

#define SCALE_A 0x7D7D7D7DU   // e8m0 125 = 2^-2  (h stored as 4*h)
#define SCALE_B 0x7B7B7B7BU   // e8m0 123 = 2^-4  (U stored as 16*U)

// barrier without vmcnt drain: LDS-ordered only (no VMEM in scan steady state)
#define BAR() asm volatile("s_waitcnt lgkmcnt(0)\n\ts_barrier" ::: "memory")

__device__ inline unsigned short f2bf(float f) {
    union { float f; uint32_t u; } v; v.f = f;
    uint32_t r = v.u + 0x7fffu + ((v.u >> 16) & 1u);
    return (unsigned short)(r >> 16);
}
__device__ inline float bf2f(unsigned short b) {
    union { uint32_t u; float f; } v; v.u = ((uint32_t)b) << 16;
    return v.f;
}
__device__ inline unsigned char f2fp8(float f) {
    int pk = __builtin_amdgcn_cvt_pk_fp8_f32(f, f, 0, false);  // OCP e4m3 on gfx950
    return (unsigned char)(pk & 0xff);
}
__device__ inline float fp8d(unsigned char b) {   // e4m3fn decode (head only)
    int s = b >> 7, e = (b >> 3) & 15, m = b & 7;
    float v = e ? ldexpf((float)(8 + m), e - 10) : ldexpf((float)m, -9);
    return s ? -v : v;
}

// ---------------------------------------------------------------------------
// Kernel 1: blocks 0..31: W -> bf16 B-frags (K=32 layout, for k_gemm).
//           blocks 32..63: U*16 -> fp8 e4m3 B-frags (K=128 layout, for k_rnn).
// fp8 frag: ufrag8[((kh*16+nt)*64+lane)*32 + j] = fp8(16*U[nt*16+(lane&15)][kh*128+(lane>>4)*32+j])
// ---------------------------------------------------------------------------
__global__ void k_pack(const float* __restrict__ W, const float* __restrict__ U,
                       unsigned short* __restrict__ wfrag, unsigned char* __restrict__ ufrag8) {
    int bid = blockIdx.x;
    if (bid < 32) {
        int idx = bid * 256 + threadIdx.x;  // 0..8191
        int lane = idx & 63;
        int tile = idx >> 6;            // kt*16 + nt
        int nt = tile & 15, kt = tile >> 4;
        int u  = nt * 16 + (lane & 15);
        int e0 = kt * 32 + (lane >> 4) * 8;
        unsigned short* dst = wfrag + (size_t)idx * 8;
        #pragma unroll
        for (int j = 0; j < 8; j++) dst[j] = f2bf(W[u * EM + e0 + j]);
    } else {
        int idx = (bid - 32) * 256 + threadIdx.x;  // 0..8191
        int jg   = idx & 3;             // 8-byte group within the 32B lane slice
        int lane = (idx >> 2) & 63;
        int tile = idx >> 8;            // kh*16 + nt, 0..31
        int nt = tile & 15, kh = tile >> 4;
        int u  = nt * 16 + (lane & 15);
        int k0 = kh * 128 + (lane >> 4) * 32 + jg * 8;
        unsigned char* dst = ufrag8 + ((size_t)tile * 64 + lane) * 32 + jg * 8;
        #pragma unroll
        for (int j = 0; j < 8; j++) dst[j] = f2fp8(16.f * U[u * UN + k0 + j]);
    }
}

// ---------------------------------------------------------------------------
// Kernel 2: xw[b][t][u] = sum_e emb[sent[b][t]][e] * W[u][e], bf16 out.
// (R8 version: LDS-transposed coalesced stores)
// ---------------------------------------------------------------------------
__global__ __launch_bounds__(256, 2) void k_gemm(
    const int* __restrict__ sent, const float* __restrict__ emb,
    const unsigned short* __restrict__ wfrag, unsigned short* __restrict__ xw)
{
    __shared__ unsigned short gt[64][264];
    int w    = threadIdx.x >> 6;
    int lane = threadIdx.x & 63;
    int m  = lane & 15;
    int kg = lane >> 4;
    int row = blockIdx.x * 64 + w * 16 + m;
    int tok = sent[row];
    const float* arow = emb + (size_t)tok * EM;

    bf16x8 a[8];
    #pragma unroll
    for (int kt = 0; kt < 8; kt++) {
        const float* p = arow + kt * 32 + kg * 8;
        float4 f0 = *(const float4*)p;
        float4 f1 = *(const float4*)(p + 4);
        bf16x8 t;
        t[0] = (short)f2bf(f0.x); t[1] = (short)f2bf(f0.y);
        t[2] = (short)f2bf(f0.z); t[3] = (short)f2bf(f0.w);
        t[4] = (short)f2bf(f1.x); t[5] = (short)f2bf(f1.y);
        t[6] = (short)f2bf(f1.z); t[7] = (short)f2bf(f1.w);
        a[kt] = t;
    }

    floatx4 acc[16];
    #pragma unroll
    for (int nt = 0; nt < 16; nt++) acc[nt] = floatx4{0.f, 0.f, 0.f, 0.f};

    #pragma unroll
    for (int kt = 0; kt < 8; kt++) {
        #pragma unroll
        for (int nt = 0; nt < 16; nt++) {
            bf16x8 bfr = *(const bf16x8*)(wfrag + ((size_t)(kt * 16 + nt) * 64 + lane) * 8);
            acc[nt] = __builtin_amdgcn_mfma_f32_16x16x32_bf16(a[kt], bfr, acc[nt], 0, 0, 0);
        }
    }

    int rloc = w * 16 + kg * 4;
    #pragma unroll
    for (int nt = 0; nt < 16; nt++) {
        #pragma unroll
        for (int r = 0; r < 4; r++) {
            gt[rloc + r][nt * 16 + m] = f2bf(acc[nt][r]);
        }
    }
    __syncthreads();

    int rowbase = blockIdx.x * 64;
    #pragma unroll
    for (int r2 = 0; r2 < 16; r2++) {
        int rr = w * 16 + r2;
        uint2 v = *(const uint2*)&gt[rr][lane * 4];
        *(uint2*)(xw + (size_t)(rowbase + rr) * UN + lane * 4) = v;
    }
}

// ---------------------------------------------------------------------------
// Kernel 3 (v8): MX-fp8 K=128 matrix-pipe scan (2 MFMA per N-tile per step).
// 128 blocks x 256 threads; wave w owns N-tiles 4w..4w+3 (units 64w..64w+63).
// U fp8 B-frags loop-invariant in regs (8 x v8i). h in LDS as fp8 (4*h),
// double-buffered. Per step: 4 broadcast ds_read_b128 A-frags + 8 scaled
// MFMA (4 tiles x 2-chain) + select + poly tanh + 1 ds_write_b8 + BAR.
// xw staged in LDS 64 steps at a time (no VMEM near barriers).
// ---------------------------------------------------------------------------
__global__ __launch_bounds__(256, 1) void k_rnn(
    const unsigned char* __restrict__ ufrag8, const unsigned short* __restrict__ xw,
    const float* __restrict__ W1, const float* __restrict__ b1,
    const float* __restrict__ W2, const float* __restrict__ b2,
    float* __restrict__ out)
{
    __shared__ __align__(16) unsigned char hb8[2][256];
    __shared__ __align__(16) unsigned short xstage[64 * 256];   // 32 KB chunk
    __shared__ float hid[32];
    const int t    = threadIdx.x;
    const int lane = t & 63;
    const int w    = t >> 6;
    const int kg   = lane >> 4;
    const int b    = blockIdx.x;

    // U fp8 B-frags -> registers: ufr8[q][kh], tile nt = 4w+q, k-half kh
    v8i ufr8[4][2];
    #pragma unroll
    for (int q = 0; q < 4; q++) {
        #pragma unroll
        for (int kh = 0; kh < 2; kh++) {
            const uint4* p = (const uint4*)(ufrag8 + ((size_t)(kh * 16 + 4 * w + q) * 64 + lane) * 32);
            union { uint4 u4[2]; v8i v; } cvt;
            cvt.u4[0] = p[0]; cvt.u4[1] = p[1];
            ufr8[q][kh] = cvt.v;
        }
    }

    const unsigned short* xwb = xw + (size_t)b * TT * UN;
    const int roff = w * 512 + lane * 8;

    // stage chunk 0 (steps 0..63)
    uint4 xr[8];
    #pragma unroll
    for (int p = 0; p < 8; p++) xr[p] = *(const uint4*)(xwb + roff + p * 2048);
    #pragma unroll
    for (int p = 0; p < 8; p++) *(uint4*)&xstage[roff + p * 2048] = xr[p];

    hb8[0][t] = 0; hb8[1][t] = 0;
    __syncthreads();

    int cur = 0;
    const float c3 = -0.33333334f, c5 = 0.13333334f, c7 = -0.05396825f, c9 = 0.02186949f;
    const floatx4 zero4 = {0.f, 0.f, 0.f, 0.f};
    const int sel = lane >> 4;

    for (int s = 0; s < TT; s++) {
        const int ls = s & 63;
        unsigned short xv = xstage[ls * 256 + t];

        // A-frags (fp8, 4*h): lane reads 32B at kg*32 for each k-half (broadcast)
        const unsigned char* hc = hb8[cur];
        union { uint4 u4[2]; v8i v; } A0, A1;
        A0.u4[0] = *(const uint4*)(hc + kg * 32);
        A0.u4[1] = *(const uint4*)(hc + kg * 32 + 16);
        A1.u4[0] = *(const uint4*)(hc + 128 + kg * 32);
        A1.u4[1] = *(const uint4*)(hc + 128 + kg * 32 + 16);

        // z for this wave's 4 N-tiles; 2-deep scaled-MFMA chain per tile
        float z[4];
        #pragma unroll
        for (int q = 0; q < 4; q++) {
            floatx4 acc = zero4;
            acc = __builtin_amdgcn_mfma_scale_f32_16x16x128_f8f6f4(
                      A0.v, ufr8[q][0], acc, 0, 0, 0, SCALE_A, 0, SCALE_B);
            acc = __builtin_amdgcn_mfma_scale_f32_16x16x128_f8f6f4(
                      A1.v, ufr8[q][1], acc, 0, 0, 0, SCALE_A, 0, SCALE_B);
            z[q] = acc[0];
        }

        float zz = (sel == 0) ? z[0] : (sel == 1) ? z[1] : (sel == 2) ? z[2] : z[3];
        zz += bf2f(xv);

        float hn;
        if (__builtin_expect(fabsf(zz) > 0.75f, 0)) {
            float e = __expf(2.f * zz);
            hn = 1.f - 2.f * __builtin_amdgcn_rcpf(e + 1.f);
        } else {
            float x2f = zz * zz;
            float p = fmaf(x2f, c9, c7);
            p = fmaf(x2f, p, c5);
            p = fmaf(x2f, p, c3);
            hn = fmaf(zz * x2f, p, zz);
        }

        hb8[cur ^ 1][t] = f2fp8(4.f * hn);

        if (ls == 60 && s + 68 <= TT) {
            const unsigned short* cb = xwb + (size_t)(s + 4) * UN;
            #pragma unroll
            for (int p = 0; p < 8; p++) xr[p] = *(const uint4*)(cb + roff + p * 2048);
        }
        if (ls == 63 && s + 65 <= TT) {
            BAR();
            #pragma unroll
            for (int p = 0; p < 8; p++) *(uint4*)&xstage[roff + p * 2048] = xr[p];
        }
        BAR();
        cur ^= 1;
    }

    // ---- head: hidden = relu(h @ W1 + b1); logits; softmax (h = fp8/4)
    if (t < 32) {
        float a = b1[t];
        for (int k = 0; k < 256; k++) a += 0.25f * fp8d(hb8[cur][k]) * W1[k * 32 + t];
        hid[t] = fmaxf(a, 0.f);
    }
    __syncthreads();
    if (t == 0) {
        float l0 = b2[0], l1 = b2[1];
        #pragma unroll
        for (int i = 0; i < 32; i++) {
            float hv = hid[i];
            l0 += hv * W2[2 * i];
            l1 += hv * W2[2 * i + 1];
        }
        float mx2 = fmaxf(l0, l1);
        float e0 = __expf(l0 - mx2), e1 = __expf(l1 - mx2);
        float inv = 1.f / (e0 + e1);
        out[2 * b]     = e0 * inv;
        out[2 * b + 1] = e1 * inv;
    }
}

extern "C" void kernel_launch(void* const* d_in, const int* in_sizes, int n_in,
                              void* d_out, int out_size, void* d_ws, size_t ws_size,
                              hipStream_t stream) {
    const int*   sent = (const int*)d_in[0];
    const float* emb  = (const float*)d_in[1];
    const float* W    = (const float*)d_in[2];
    const float* U    = (const float*)d_in[3];
    const float* W1   = (const float*)d_in[4];
    const float* b1   = (const float*)d_in[5];
    const float* W2   = (const float*)d_in[6];
    const float* b2   = (const float*)d_in[7];
    float* out = (float*)d_out;

    unsigned short* xw     = (unsigned short*)d_ws;                                     // 32 MB bf16 [B][T][U]
    unsigned short* wfrag  = (unsigned short*)((char*)d_ws + (size_t)NB * TT * UN * 2); // 128 KB
    unsigned char*  ufrag8 = (unsigned char*)((char*)d_ws + (size_t)NB * TT * UN * 2 + (size_t)UN * EM * 2); // 64 KB

    k_pack<<<64, 256, 0, stream>>>(W, U, wfrag, ufrag8);
    k_gemm<<<(NB * TT) / 64, 256, 0, stream>>>(sent, emb, wfrag, xw);
    k_rnn<<<NB, 256, 0, stream>>>(ufrag8, xw, W1, b1, W2, b2, out);
}